// Round 2
// baseline (362.887 us; speedup 1.0000x reference)
//
#include <hip/hip_runtime.h>
#include <stdint.h>
#include <math.h>

// RG-LRU: B=4, L=4096, D=1024.
//   r = sigmoid(x @ Wa^T + ba); i = sigmoid(x @ Wx^T + bx)
//   a_t = exp(8 * r * log(sigmoid(lmbd)));  b_t = sqrt(1-a_t^2) * i * x
//   h_t = a_t*h_{t-1} + b_t  (scan over L per (b,d) channel)
//
// R2: conflict-free LDS layout via lane-permuted global_load_lds staging
// (fragment reads become base + lane*16 — contiguous, 0 bank conflicts);
// g stored as bf16 to cut scan read traffic.

#define D_DIM 1024
#define L_DIM 4096
#define B_DIM 4
#define M_DIM (B_DIM * L_DIM)   // 16384 rows
#define N_DIM (2 * D_DIM)       // 2048 (Wa cols then Wx cols)
#define K_DIM D_DIM             // 1024
#define NC 32
#define CL (L_DIM / NC)         // 128

typedef __attribute__((ext_vector_type(8))) short short8;
typedef __attribute__((ext_vector_type(4))) short short4v;
typedef __attribute__((ext_vector_type(4))) float float4v;

__device__ __forceinline__ unsigned short f2bf(float f) {
  unsigned u = __float_as_uint(f);
  u += 0x7fffu + ((u >> 16) & 1u);   // round-nearest-even
  return (unsigned short)(u >> 16);
}
__device__ __forceinline__ float bf2f(unsigned short h) {
  return __uint_as_float((unsigned)h << 16);
}

__global__ void cvt_bf16(const float* __restrict__ in, short* __restrict__ out, int n4) {
  int i = blockIdx.x * blockDim.x + threadIdx.x;
  if (i >= n4) return;
  float4v v = ((const float4v*)in)[i];
  short4v o;
  o.x = (short)f2bf(v.x);
  o.y = (short)f2bf(v.y);
  o.z = (short)f2bf(v.z);
  o.w = (short)f2bf(v.w);
  ((short4v*)out)[i] = o;
}

// 128x128 tile, BK=32, 256 threads = 4 waves, each wave 64x64 via 4x4
// mfma_f32_16x16x32_bf16. LDS layout = staging lane order:
//   group g (16 rows) at g*1024B; within group, addr = (kchunk*16+row)*16B.
// Fragment read for group g is then As + g*1024 + lane*16 — conflict-free.
__global__ __launch_bounds__(256, 2) void gemm_gates(
    const short* __restrict__ Xb,    // [16384,1024] bf16
    const short* __restrict__ Wb,    // [2048,1024] bf16 ([Wa;Wx])
    const float* __restrict__ xf,    // original fp32 x (for g = i*x)
    const float* __restrict__ ba,
    const float* __restrict__ bx,
    const float* __restrict__ lmbd,
    float* __restrict__ a_out,       // [16384,1024] a_t  (fp32)
    unsigned short* __restrict__ g_out) // [16384,1024] i*x (bf16)
{
  __shared__ __align__(16) short As[128 * 32];  // 8 KB
  __shared__ __align__(16) short Bs[128 * 32];  // 8 KB

  const int tile_m = blockIdx.x * 128;
  const int tile_n = blockIdx.y * 128;   // in [0,2048)
  const int tid  = threadIdx.x;
  const int wave = tid >> 6;
  const int lane = tid & 63;
  const int row16 = lane & 15;
  const int quad  = lane >> 4;
  const int wave_m = (wave & 1) * 64;
  const int wave_n = (wave >> 1) * 64;

  float4v acc[4][4] = {};

  // Permuted staging: lane i covers (row = i&15, kchunk = i>>4).
  const short* Ag = Xb + (size_t)(tile_m + wave * 16 + row16) * K_DIM + quad * 8;
  const short* Bg = Wb + (size_t)(tile_n + wave * 16 + row16) * K_DIM + quad * 8;
  char* AsB = (char*)As;
  char* BsB = (char*)Bs;

  for (int k0 = 0; k0 < K_DIM; k0 += 32) {
#pragma unroll
    for (int p = 0; p < 2; ++p) {
      // group index G = p*4 + wave (rows [G*16, G*16+16))
      __builtin_amdgcn_global_load_lds(
          (const __attribute__((address_space(1))) void*)(Ag + (size_t)p * 64 * K_DIM + k0),
          (__attribute__((address_space(3))) void*)(AsB + (p * 4 + wave) * 1024),
          16, 0, 0);
      __builtin_amdgcn_global_load_lds(
          (const __attribute__((address_space(1))) void*)(Bg + (size_t)p * 64 * K_DIM + k0),
          (__attribute__((address_space(3))) void*)(BsB + (p * 4 + wave) * 1024),
          16, 0, 0);
    }
    __syncthreads();

    short8 af[4], bfr[4];
#pragma unroll
    for (int i = 0; i < 4; ++i)   // group = wave_m/16 + i ; addr = group*512 + lane*8 (shorts)
      af[i] = *(const short8*)&As[((wave & 1) * 4 + i) * 512 + lane * 8];
#pragma unroll
    for (int i = 0; i < 4; ++i)
      bfr[i] = *(const short8*)&Bs[((wave >> 1) * 4 + i) * 512 + lane * 8];

#pragma unroll
    for (int mi = 0; mi < 4; ++mi)
#pragma unroll
      for (int ni = 0; ni < 4; ++ni)
        acc[mi][ni] = __builtin_amdgcn_mfma_f32_16x16x32_bf16(af[mi], bfr[ni], acc[mi][ni], 0, 0, 0);
    __syncthreads();
  }

  // Epilogue. C/D layout: col = lane&15, row = quad*4 + reg.
  const int base_row = tile_m + wave_m + quad * 4;
  if (tile_n < D_DIM) {
    // r-gate half: a_t = exp(8 * sigmoid(z) * log(sigmoid(lmbd)))
#pragma unroll
    for (int ni = 0; ni < 4; ++ni) {
      int ch = tile_n + wave_n + ni * 16 + row16;
      float bias = ba[ch];
      float la = -log1pf(expf(-lmbd[ch]));   // log(sigmoid(lmbd)), stable for lmbd>0
#pragma unroll
      for (int mi = 0; mi < 4; ++mi) {
        int r0 = base_row + mi * 16;
#pragma unroll
        for (int r = 0; r < 4; ++r) {
          float z = acc[mi][ni][r] + bias;
          float rg = 1.0f / (1.0f + expf(-z));
          a_out[(size_t)(r0 + r) * D_DIM + ch] = expf(8.0f * rg * la);
        }
      }
    }
  } else {
    // i-gate half: g = sigmoid(z) * x  (stored bf16)
#pragma unroll
    for (int ni = 0; ni < 4; ++ni) {
      int ch = tile_n - D_DIM + wave_n + ni * 16 + row16;
      float bias = bx[ch];
#pragma unroll
      for (int mi = 0; mi < 4; ++mi) {
        int r0 = base_row + mi * 16;
#pragma unroll
        for (int r = 0; r < 4; ++r) {
          float z = acc[mi][ni][r] + bias;
          float ig = 1.0f / (1.0f + expf(-z));
          g_out[(size_t)(r0 + r) * D_DIM + ch] = f2bf(ig * xf[(size_t)(r0 + r) * D_DIM + ch]);
        }
      }
    }
  }
}

// Phase 1: per-chunk composition (P = prod a, Q = chunk-local scan from 0).
__global__ void scan_phase1(const float* __restrict__ a, const unsigned short* __restrict__ g,
                            float* __restrict__ P, float* __restrict__ Q) {
  int d = blockIdx.x * 256 + threadIdx.x;
  int c = blockIdx.y;
  int b = blockIdx.z;
  const size_t base = ((size_t)(b * L_DIM + c * CL)) * D_DIM + d;
  float Pv = 1.0f, Qv = 0.0f;
#pragma unroll 4
  for (int t = 0; t < CL; ++t) {
    float at = a[base + (size_t)t * D_DIM];
    float gv = bf2f(g[base + (size_t)t * D_DIM]);
    float bt = sqrtf(fmaxf(1.0f - at * at, 0.0f)) * gv;
    Qv = fmaf(at, Qv, bt);
    Pv *= at;
  }
  int idx = (b * NC + c) * D_DIM + d;
  P[idx] = Pv;
  Q[idx] = Qv;
}

// Phase 2: prefix over the NC chunks per channel. 4096 threads.
__global__ void scan_phase2(const float* __restrict__ P, const float* __restrict__ Q,
                            float* __restrict__ Hin) {
  int tid = blockIdx.x * 256 + threadIdx.x;   // 0..4095
  int b = tid >> 10;
  int d = tid & 1023;
  float H = 0.0f;
#pragma unroll
  for (int c = 0; c < NC; ++c) {
    int idx = (b * NC + c) * D_DIM + d;
    Hin[idx] = H;                 // h entering chunk c
    H = fmaf(P[idx], H, Q[idx]);
  }
}

// Phase 3: replay each chunk from its correct incoming h, write y.
__global__ void scan_phase3(const float* __restrict__ a, const unsigned short* __restrict__ g,
                            const float* __restrict__ Hin, float* __restrict__ y) {
  int d = blockIdx.x * 256 + threadIdx.x;
  int c = blockIdx.y;
  int b = blockIdx.z;
  const size_t base = ((size_t)(b * L_DIM + c * CL)) * D_DIM + d;
  float h = Hin[(b * NC + c) * D_DIM + d];
#pragma unroll 4
  for (int t = 0; t < CL; ++t) {
    float at = a[base + (size_t)t * D_DIM];
    float gv = bf2f(g[base + (size_t)t * D_DIM]);
    float bt = sqrtf(fmaxf(1.0f - at * at, 0.0f)) * gv;
    h = fmaf(at, h, bt);
    y[base + (size_t)t * D_DIM] = h;
  }
}

extern "C" void kernel_launch(void* const* d_in, const int* in_sizes, int n_in,
                              void* d_out, int out_size, void* d_ws, size_t ws_size,
                              hipStream_t stream) {
  const float* x    = (const float*)d_in[0];   // [4,4096,1024]
  const float* Wa   = (const float*)d_in[1];   // [1024,1024]
  const float* Wx   = (const float*)d_in[2];
  const float* ba   = (const float*)d_in[3];
  const float* bx   = (const float*)d_in[4];
  const float* lmbd = (const float*)d_in[5];
  float* y = (float*)d_out;                    // [4,4096,1024] fp32

  // Workspace layout (~134 MiB):
  char* ws = (char*)d_ws;
  short* Xb             = (short*)ws;                   // 32 MiB  bf16 x
  short* Wb             = (short*)(ws + 33554432);      //  4 MiB  bf16 [Wa;Wx]
  float* a_buf          = (float*)(ws + 37748736);      // 64 MiB  a_t fp32
  unsigned short* g_buf = (unsigned short*)(ws + 104857600); // 32 MiB g bf16
  float* P              = (float*)(ws + 138412032);     // 512 KiB
  float* Q              = (float*)(ws + 138936320);     // 512 KiB
  float* Hin            = (float*)(ws + 139460608);     // 512 KiB

  // fp32 -> bf16 converts
  cvt_bf16<<<16384, 256, 0, stream>>>(x,  Xb, M_DIM * K_DIM / 4);
  cvt_bf16<<<1024,  256, 0, stream>>>(Wa, Wb, D_DIM * D_DIM / 4);
  cvt_bf16<<<1024,  256, 0, stream>>>(Wx, Wb + (size_t)D_DIM * D_DIM, D_DIM * D_DIM / 4);

  // fused dual GEMM + gate epilogue
  dim3 gg(M_DIM / 128, N_DIM / 128);   // (128, 16)
  gemm_gates<<<gg, 256, 0, stream>>>(Xb, Wb, x, ba, bx, lmbd, a_buf, g_buf);

  // chunked scan
  dim3 sg(D_DIM / 256, NC, B_DIM);     // (4, 32, 4)
  scan_phase1<<<sg, 256, 0, stream>>>(a_buf, g_buf, P, Q);
  scan_phase2<<<16, 256, 0, stream>>>(P, Q, Hin);
  scan_phase3<<<sg, 256, 0, stream>>>(a_buf, g_buf, Hin, y);
}

// Round 3
// 350.648 us; speedup vs baseline: 1.0349x; 1.0349x over previous
//
#include <hip/hip_runtime.h>
#include <stdint.h>
#include <math.h>

// RG-LRU: B=4, L=4096, D=1024.
//   r = sigmoid(x @ Wa^T + ba); i = sigmoid(x @ Wx^T + bx)
//   a_t = sigma(lmbd)^(8r);  b_t = sqrt(1-a_t^2) * i * x
//   h_t = a_t*h_{t-1} + b_t  (scan over L per (b,d) channel)
//
// R3: (1) X/W pre-swizzled in memory to tile-packed order so GEMM staging is
// lane-contiguous 1KB/wave (coalesced) AND the forced global_load_lds layout
// is conflict-free (fragment read = base + lane*16). (2) Epilogue uses HW
// transcendentals (v_exp/v_log/v_rcp) in log2 domain. (3) scan_phase2 folded
// into phase3 (per-block chunk-prefix lookback).

#define D_DIM 1024
#define L_DIM 4096
#define B_DIM 4
#define M_DIM (B_DIM * L_DIM)   // 16384 rows
#define N_DIM (2 * D_DIM)       // 2048 (Wa cols then Wx cols)
#define K_DIM D_DIM             // 1024
#define NC 32
#define CL (L_DIM / NC)         // 128
#define L2E 1.4426950408889634f

typedef __attribute__((ext_vector_type(8))) short short8;
typedef __attribute__((ext_vector_type(4))) float float4v;

__device__ __forceinline__ unsigned short f2bf(float f) {
  unsigned u = __float_as_uint(f);
  u += 0x7fffu + ((u >> 16) & 1u);   // round-nearest-even
  return (unsigned short)(u >> 16);
}
__device__ __forceinline__ float bf2f(unsigned short h) {
  return __uint_as_float((unsigned)h << 16);
}

// Pack fp32 [rows][1024] -> swizzled bf16: group16 R, k0 (32B-chunk of K=32),
// kc (16B sub-chunk), r (row in group):  off16B = ((R*32+k0)*4 + kc)*16 + r.
// Output-indexed: each thread emits one contiguous 16B group (writes fully
// coalesced 1KB/wave; reads are 32B granules, TA merges lines).
__global__ void pack_swz(const float* __restrict__ in, short* __restrict__ out, int n16) {
  int t = blockIdx.x * 256 + threadIdx.x;
  if (t >= n16) return;
  int r  = t & 15;
  int kc = (t >> 4) & 3;
  int k0 = (t >> 6) & 31;
  int R  = t >> 11;
  int m = R * 16 + r;
  int k = (k0 * 4 + kc) * 8;
  const float4v* src = (const float4v*)(in + (size_t)m * 1024 + k);
  float4v v0 = src[0], v1 = src[1];
  short8 o;
  o[0] = (short)f2bf(v0.x); o[1] = (short)f2bf(v0.y);
  o[2] = (short)f2bf(v0.z); o[3] = (short)f2bf(v0.w);
  o[4] = (short)f2bf(v1.x); o[5] = (short)f2bf(v1.y);
  o[6] = (short)f2bf(v1.z); o[7] = (short)f2bf(v1.w);
  ((short8*)out)[t] = o;
}

// 128x128 tile, BK=32, 256 threads = 4 waves, each wave 64x64 via 4x4
// mfma_f32_16x16x32_bf16. Staging: wave stages group G=p*4+wave from
// swizzled source at ((Rg*32+kk)*64 + lane)*8 shorts — contiguous 1KB/wave.
// LDS layout (= lane order): group G at G*1024B, fragment read G*512+lane*8
// shorts — conflict-free (verified R2: conflicts == 0, math correct).
__global__ __launch_bounds__(256, 4) void gemm_gates(
    const short* __restrict__ Xs,    // swizzled [16384,1024] bf16
    const short* __restrict__ Ws,    // swizzled [2048,1024] bf16 ([Wa;Wx])
    const float* __restrict__ xf,    // original fp32 x (for g = i*x)
    const float* __restrict__ ba,
    const float* __restrict__ bx,
    const float* __restrict__ lmbd,
    float* __restrict__ a_out,          // [16384,1024] a_t (fp32)
    unsigned short* __restrict__ g_out) // [16384,1024] i*x (bf16)
{
  __shared__ __align__(16) short As[128 * 32];  // 8 KB
  __shared__ __align__(16) short Bs[128 * 32];  // 8 KB

  const int tile_m = blockIdx.x * 128;
  const int tile_n = blockIdx.y * 128;   // in [0,2048)
  const int tid  = threadIdx.x;
  const int wave = tid >> 6;
  const int lane = tid & 63;
  const int row16 = lane & 15;
  const int quad  = lane >> 4;
  const int wave_m = (wave & 1) * 64;
  const int wave_n = (wave >> 1) * 64;

  float4v acc[4][4] = {};

  char* AsB = (char*)As;
  char* BsB = (char*)Bs;

  for (int kk = 0; kk < 32; ++kk) {
#pragma unroll
    for (int p = 0; p < 2; ++p) {
      const int G = p * 4 + wave;                 // row group [G*16, +16)
      const size_t RgA = (size_t)((tile_m >> 4) + G);
      const size_t RgB = (size_t)((tile_n >> 4) + G);
      __builtin_amdgcn_global_load_lds(
          (const __attribute__((address_space(1))) void*)(Xs + ((RgA * 32 + kk) * 64 + lane) * 8),
          (__attribute__((address_space(3))) void*)(AsB + G * 1024),
          16, 0, 0);
      __builtin_amdgcn_global_load_lds(
          (const __attribute__((address_space(1))) void*)(Ws + ((RgB * 32 + kk) * 64 + lane) * 8),
          (__attribute__((address_space(3))) void*)(BsB + G * 1024),
          16, 0, 0);
    }
    __syncthreads();

    short8 af[4], bfr[4];
#pragma unroll
    for (int i = 0; i < 4; ++i)
      af[i] = *(const short8*)&As[((wave & 1) * 4 + i) * 512 + lane * 8];
#pragma unroll
    for (int i = 0; i < 4; ++i)
      bfr[i] = *(const short8*)&Bs[((wave >> 1) * 4 + i) * 512 + lane * 8];

#pragma unroll
    for (int mi = 0; mi < 4; ++mi)
#pragma unroll
      for (int ni = 0; ni < 4; ++ni)
        acc[mi][ni] = __builtin_amdgcn_mfma_f32_16x16x32_bf16(af[mi], bfr[ni], acc[mi][ni], 0, 0, 0);
    __syncthreads();
  }

  // Epilogue. C/D layout: col = lane&15, row = quad*4 + reg. HW transcendentals.
  const int base_row = tile_m + wave_m + quad * 4;
  if (tile_n < D_DIM) {
    // r-gate half: a = exp2( sigmoid(z) * 8*log2(sigmoid(lmbd)) )
#pragma unroll
    for (int ni = 0; ni < 4; ++ni) {
      int ch = tile_n + wave_n + ni * 16 + row16;
      float bias = ba[ch];
      float lam = lmbd[ch];
      float la8 = -8.0f * __builtin_amdgcn_logf(1.0f + __builtin_amdgcn_exp2f(-lam * L2E));
#pragma unroll
      for (int mi = 0; mi < 4; ++mi) {
        int r0 = base_row + mi * 16;
#pragma unroll
        for (int r = 0; r < 4; ++r) {
          float z = acc[mi][ni][r] + bias;
          float s = __builtin_amdgcn_rcpf(1.0f + __builtin_amdgcn_exp2f(-z * L2E));
          a_out[(size_t)(r0 + r) * D_DIM + ch] = __builtin_amdgcn_exp2f(s * la8);
        }
      }
    }
  } else {
    // i-gate half: g = sigmoid(z) * x  (stored bf16)
#pragma unroll
    for (int ni = 0; ni < 4; ++ni) {
      int ch = tile_n - D_DIM + wave_n + ni * 16 + row16;
      float bias = bx[ch];
#pragma unroll
      for (int mi = 0; mi < 4; ++mi) {
        int r0 = base_row + mi * 16;
#pragma unroll
        for (int r = 0; r < 4; ++r) {
          float z = acc[mi][ni][r] + bias;
          float s = __builtin_amdgcn_rcpf(1.0f + __builtin_amdgcn_exp2f(-z * L2E));
          g_out[(size_t)(r0 + r) * D_DIM + ch] = f2bf(s * xf[(size_t)(r0 + r) * D_DIM + ch]);
        }
      }
    }
  }
}

// Phase 1: per-chunk composition (P = prod a, Q = chunk-local scan from 0).
__global__ void scan_phase1(const float* __restrict__ a, const unsigned short* __restrict__ g,
                            float* __restrict__ P, float* __restrict__ Q) {
  int d = blockIdx.x * 256 + threadIdx.x;
  int c = blockIdx.y;
  int b = blockIdx.z;
  const size_t base = ((size_t)(b * L_DIM + c * CL)) * D_DIM + d;
  float Pv = 1.0f, Qv = 0.0f;
#pragma unroll 4
  for (int t = 0; t < CL; ++t) {
    float at = a[base + (size_t)t * D_DIM];
    float gv = bf2f(g[base + (size_t)t * D_DIM]);
    float bt = sqrtf(fmaxf(1.0f - at * at, 0.0f)) * gv;
    Qv = fmaf(at, Qv, bt);
    Pv *= at;
  }
  int idx = (b * NC + c) * D_DIM + d;
  P[idx] = Pv;
  Q[idx] = Qv;
}

// Phase 3: per-block lookback prefix over earlier chunks, then replay chunk,
// write y. (Replaces separate phase-2 kernel.)
__global__ void scan_phase3(const float* __restrict__ a, const unsigned short* __restrict__ g,
                            const float* __restrict__ P, const float* __restrict__ Q,
                            float* __restrict__ y) {
  int d = blockIdx.x * 256 + threadIdx.x;
  int c = blockIdx.y;
  int b = blockIdx.z;
  float h = 0.0f;
#pragma unroll 4
  for (int cc = 0; cc < c; ++cc) {
    int idx = (b * NC + cc) * D_DIM + d;
    h = fmaf(P[idx], h, Q[idx]);
  }
  const size_t base = ((size_t)(b * L_DIM + c * CL)) * D_DIM + d;
#pragma unroll 4
  for (int t = 0; t < CL; ++t) {
    float at = a[base + (size_t)t * D_DIM];
    float gv = bf2f(g[base + (size_t)t * D_DIM]);
    float bt = sqrtf(fmaxf(1.0f - at * at, 0.0f)) * gv;
    h = fmaf(at, h, bt);
    y[base + (size_t)t * D_DIM] = h;
  }
}

extern "C" void kernel_launch(void* const* d_in, const int* in_sizes, int n_in,
                              void* d_out, int out_size, void* d_ws, size_t ws_size,
                              hipStream_t stream) {
  const float* x    = (const float*)d_in[0];   // [4,4096,1024]
  const float* Wa   = (const float*)d_in[1];   // [1024,1024]
  const float* Wx   = (const float*)d_in[2];
  const float* ba   = (const float*)d_in[3];
  const float* bx   = (const float*)d_in[4];
  const float* lmbd = (const float*)d_in[5];
  float* y = (float*)d_out;                    // [4,4096,1024] fp32

  // Workspace layout (~133 MiB):
  char* ws = (char*)d_ws;
  short* Xs             = (short*)ws;                        // 32 MiB swizzled bf16 x
  short* Wsz            = (short*)(ws + 33554432);           //  4 MiB swizzled bf16 [Wa;Wx]
  float* a_buf          = (float*)(ws + 37748736);           // 64 MiB a_t fp32
  unsigned short* g_buf = (unsigned short*)(ws + 104857600); // 32 MiB g bf16
  float* P              = (float*)(ws + 138412032);          // 512 KiB
  float* Q              = (float*)(ws + 138936320);          // 512 KiB

  // fp32 -> swizzled bf16 packs
  pack_swz<<<8192, 256, 0, stream>>>(x,  Xs, M_DIM * K_DIM / 8);
  pack_swz<<<512,  256, 0, stream>>>(Wa, Wsz, D_DIM * K_DIM / 8);
  pack_swz<<<512,  256, 0, stream>>>(Wx, Wsz + (size_t)D_DIM * K_DIM, D_DIM * K_DIM / 8);

  // fused dual GEMM + gate epilogue
  dim3 gg(M_DIM / 128, N_DIM / 128);   // (128, 16)
  gemm_gates<<<gg, 256, 0, stream>>>(Xs, Wsz, x, ba, bx, lmbd, a_buf, g_buf);

  // chunked scan
  dim3 sg(D_DIM / 256, NC, B_DIM);     // (4, 32, 4)
  scan_phase1<<<sg, 256, 0, stream>>>(a_buf, g_buf, P, Q);
  scan_phase3<<<sg, 256, 0, stream>>>(a_buf, g_buf, P, Q, y);
}

// Round 4
// 250.494 us; speedup vs baseline: 1.4487x; 1.3998x over previous
//
#include <hip/hip_runtime.h>
#include <stdint.h>
#include <math.h>

// RG-LRU: B=4, L=4096, D=1024.
//   r = sigmoid(x @ Wa^T + ba); i = sigmoid(x @ Wx^T + bx)
//   e = 8*r*log2(sigmoid(lmbd));  a = exp2(e);  b = sqrt(1-a^2)*i*x
//   h_t = a_t*h_{t-1} + b_t
//
// R4: LDS-transpose epilogue (kills 2x write/read granule amplification),
// e stored fp16 log2-domain, grid n-fastest for X reuse, single pack kernel.

#define D_DIM 1024
#define L_DIM 4096
#define B_DIM 4
#define M_DIM (B_DIM * L_DIM)   // 16384
#define N_DIM (2 * D_DIM)       // 2048
#define K_DIM D_DIM             // 1024
#define NC 32
#define CL (L_DIM / NC)         // 128
#define L2E 1.4426950408889634f

typedef __attribute__((ext_vector_type(8))) short short8;
typedef __attribute__((ext_vector_type(4))) short short4v;
typedef __attribute__((ext_vector_type(4))) float float4v;

__device__ __forceinline__ unsigned short f2bf(float f) {
  unsigned u = __float_as_uint(f);
  u += 0x7fffu + ((u >> 16) & 1u);
  return (unsigned short)(u >> 16);
}
__device__ __forceinline__ float bf2f(unsigned short h) {
  return __uint_as_float((unsigned)h << 16);
}
__device__ __forceinline__ short f2h(float f) {
  _Float16 h = (_Float16)f;
  return __builtin_bit_cast(short, h);
}

#define NX16 (M_DIM * K_DIM / 8)       // 2097152 x-groups
#define NW16 (N_DIM * K_DIM / 8)       // 262144 w-groups

// Pack fp32 [rows][1024] -> swizzled bf16, 16B group index:
//   off16 = ((R*32 + k0)*4 + kc)*16 + r,  row = R*16+r, k = (k0*4+kc)*8.
// One kernel packs x -> Xs and [Wa;Wx] -> Ws.
__global__ void pack_all(const float* __restrict__ x, const float* __restrict__ Wa,
                         const float* __restrict__ Wx, short* __restrict__ Xs,
                         short* __restrict__ Ws) {
  int t = blockIdx.x * 256 + threadIdx.x;
  const float* src;
  short8* dst;
  int u;
  if (t < NX16) {
    u = t; src = x; dst = (short8*)Xs;
  } else {
    u = t - NX16;
    if (u >= NW16) return;
    dst = (short8*)Ws;
    int row = ((u >> 11) << 4) | (u & 15);
    src = (row < D_DIM) ? Wa : (Wx - (size_t)D_DIM * K_DIM);
  }
  int r  = u & 15;
  int kc = (u >> 4) & 3;
  int k0 = (u >> 6) & 31;
  int R  = u >> 11;
  int m = R * 16 + r;
  int k = (k0 * 4 + kc) * 8;
  const float4v* s4 = (const float4v*)(src + (size_t)m * 1024 + k);
  float4v v0 = s4[0], v1 = s4[1];
  short8 o;
  o[0] = (short)f2bf(v0.x); o[1] = (short)f2bf(v0.y);
  o[2] = (short)f2bf(v0.z); o[3] = (short)f2bf(v0.w);
  o[4] = (short)f2bf(v1.x); o[5] = (short)f2bf(v1.y);
  o[6] = (short)f2bf(v1.z); o[7] = (short)f2bf(v1.w);
  dst[u] = o;
}

// 128x128 tile, BK=32, 4 waves, 4x4 mfma_f32_16x16x32_bf16 per wave.
// Staging + fragment layout as R3 (conflict-free, coalesced).
// Epilogue: per-wave LDS transpose (reusing staging LDS) -> lane-contiguous
// 128B-granule-full stores; writes e (fp16) / g (bf16).
__global__ __launch_bounds__(256, 4) void gemm_gates(
    const short* __restrict__ Xs,
    const short* __restrict__ Ws,
    const float* __restrict__ xf,
    const float* __restrict__ ba,
    const float* __restrict__ bx,
    const float* __restrict__ lmbd,
    short* __restrict__ e_out,          // [16384,1024] fp16: 8*r*log2(sig(lmbd))
    unsigned short* __restrict__ g_out) // [16384,1024] bf16: i*x
{
  __shared__ __align__(16) char smem[17664];  // 16KB staging, 17.3KB epilogue

  const int tile_n = blockIdx.x * 128;   // n fastest -> X panel shared by 16 blocks
  const int tile_m = blockIdx.y * 128;
  const int tid  = threadIdx.x;
  const int wave = tid >> 6;
  const int lane = tid & 63;
  const int row16 = lane & 15;
  const int quad  = lane >> 4;
  const int wave_m = (wave & 1) * 64;
  const int wave_n = (wave >> 1) * 64;

  short* As = (short*)smem;
  short* Bs = (short*)(smem + 8192);
  char* AsB = smem;
  char* BsB = smem + 8192;

  float4v acc[4][4] = {};

  for (int kk = 0; kk < 32; ++kk) {
#pragma unroll
    for (int p = 0; p < 2; ++p) {
      const int G = p * 4 + wave;
      const size_t RgA = (size_t)((tile_m >> 4) + G);
      const size_t RgB = (size_t)((tile_n >> 4) + G);
      __builtin_amdgcn_global_load_lds(
          (const __attribute__((address_space(1))) void*)(Xs + ((RgA * 32 + kk) * 64 + lane) * 8),
          (__attribute__((address_space(3))) void*)(AsB + G * 1024),
          16, 0, 0);
      __builtin_amdgcn_global_load_lds(
          (const __attribute__((address_space(1))) void*)(Ws + ((RgB * 32 + kk) * 64 + lane) * 8),
          (__attribute__((address_space(3))) void*)(BsB + G * 1024),
          16, 0, 0);
    }
    __syncthreads();

    short8 af[4], bfr[4];
#pragma unroll
    for (int i = 0; i < 4; ++i)
      af[i] = *(const short8*)&As[((wave & 1) * 4 + i) * 512 + lane * 8];
#pragma unroll
    for (int i = 0; i < 4; ++i)
      bfr[i] = *(const short8*)&Bs[((wave >> 1) * 4 + i) * 512 + lane * 8];

#pragma unroll
    for (int mi = 0; mi < 4; ++mi)
#pragma unroll
      for (int ni = 0; ni < 4; ++ni)
        acc[mi][ni] = __builtin_amdgcn_mfma_f32_16x16x32_bf16(af[mi], bfr[ni], acc[mi][ni], 0, 0, 0);
    __syncthreads();   // also guards smem reuse by the epilogue below
  }

  // ---- Epilogue: per-wave 64x64 transpose through LDS (stride 68 floats) ----
  float* Ts = (float*)smem + (size_t)wave * (16 * 68);
  const int colg = (lane & 15) * 4;   // 4-col group within wave's 64 cols
  const int rrow = lane >> 4;         // 0..3
  const bool is_a = (tile_n < D_DIM);
  const int ch0 = (is_a ? tile_n : tile_n - D_DIM) + wave_n + colg;

  float4v bias4, la84;
  if (is_a) {
    bias4 = *(const float4v*)(ba + ch0);
    float4v lm4 = *(const float4v*)(lmbd + ch0);
#pragma unroll
    for (int k = 0; k < 4; ++k)
      la84[k] = -8.0f * __builtin_amdgcn_logf(1.0f + __builtin_amdgcn_exp2f(-lm4[k] * L2E));
  } else {
    bias4 = *(const float4v*)(bx + ch0);
  }

#pragma unroll
  for (int mi = 0; mi < 4; ++mi) {
#pragma unroll
    for (int ni = 0; ni < 4; ++ni)
#pragma unroll
      for (int r = 0; r < 4; ++r)
        Ts[(quad * 4 + r) * 68 + ni * 16 + row16] = acc[mi][ni][r];
#pragma unroll
    for (int j = 0; j < 4; ++j) {
      int lr = j * 4 + rrow;                     // 0..15 local row
      float4v z = *(const float4v*)&Ts[lr * 68 + colg];
      size_t gm = (size_t)(tile_m + wave_m + mi * 16 + lr);
      short4v o;
      if (is_a) {
#pragma unroll
        for (int k = 0; k < 4; ++k) {
          float s = __builtin_amdgcn_rcpf(1.0f + __builtin_amdgcn_exp2f(-(z[k] + bias4[k]) * L2E));
          o[k] = f2h(s * la84[k]);
        }
        *(short4v*)(e_out + gm * D_DIM + ch0) = o;
      } else {
        float4v xv = *(const float4v*)(xf + gm * D_DIM + ch0);
#pragma unroll
        for (int k = 0; k < 4; ++k) {
          float s = __builtin_amdgcn_rcpf(1.0f + __builtin_amdgcn_exp2f(-(z[k] + bias4[k]) * L2E));
          o[k] = (short)f2bf(s * xv[k]);
        }
        *(short4v*)((short*)g_out + gm * D_DIM + ch0) = o;
      }
    }
  }
}

// Phase 1: per-chunk (P = prod a, Q = local scan from 0). a = exp2(e).
__global__ void scan_phase1(const short* __restrict__ e, const unsigned short* __restrict__ g,
                            float* __restrict__ P, float* __restrict__ Q) {
  int d = blockIdx.x * 256 + threadIdx.x;
  int c = blockIdx.y;
  int b = blockIdx.z;
  const size_t base = ((size_t)(b * L_DIM + c * CL)) * D_DIM + d;
  float Pv = 1.0f, Qv = 0.0f;
#pragma unroll 4
  for (int t = 0; t < CL; ++t) {
    float ev = (float)__builtin_bit_cast(_Float16, e[base + (size_t)t * D_DIM]);
    float at = __builtin_amdgcn_exp2f(ev);
    float gv = bf2f(g[base + (size_t)t * D_DIM]);
    float bt = sqrtf(fmaxf(1.0f - at * at, 0.0f)) * gv;
    Qv = fmaf(at, Qv, bt);
    Pv *= at;
  }
  int idx = (b * NC + c) * D_DIM + d;
  P[idx] = Pv;
  Q[idx] = Qv;
}

// Phase 3: lookback prefix over earlier chunks, replay chunk, write y.
__global__ void scan_phase3(const short* __restrict__ e, const unsigned short* __restrict__ g,
                            const float* __restrict__ P, const float* __restrict__ Q,
                            float* __restrict__ y) {
  int d = blockIdx.x * 256 + threadIdx.x;
  int c = blockIdx.y;
  int b = blockIdx.z;
  float h = 0.0f;
#pragma unroll 4
  for (int cc = 0; cc < c; ++cc) {
    int idx = (b * NC + cc) * D_DIM + d;
    h = fmaf(P[idx], h, Q[idx]);
  }
  const size_t base = ((size_t)(b * L_DIM + c * CL)) * D_DIM + d;
#pragma unroll 4
  for (int t = 0; t < CL; ++t) {
    float ev = (float)__builtin_bit_cast(_Float16, e[base + (size_t)t * D_DIM]);
    float at = __builtin_amdgcn_exp2f(ev);
    float gv = bf2f(g[base + (size_t)t * D_DIM]);
    float bt = sqrtf(fmaxf(1.0f - at * at, 0.0f)) * gv;
    h = fmaf(at, h, bt);
    y[base + (size_t)t * D_DIM] = h;
  }
}

extern "C" void kernel_launch(void* const* d_in, const int* in_sizes, int n_in,
                              void* d_out, int out_size, void* d_ws, size_t ws_size,
                              hipStream_t stream) {
  const float* x    = (const float*)d_in[0];
  const float* Wa   = (const float*)d_in[1];
  const float* Wx   = (const float*)d_in[2];
  const float* ba   = (const float*)d_in[3];
  const float* bx   = (const float*)d_in[4];
  const float* lmbd = (const float*)d_in[5];
  float* y = (float*)d_out;

  char* ws = (char*)d_ws;
  short* Xs             = (short*)ws;                        // 32 MiB swizzled bf16 x
  short* Wsz            = (short*)(ws + 33554432);           //  4 MiB swizzled bf16 [Wa;Wx]
  short* e_buf          = (short*)(ws + 37748736);           // 32 MiB fp16 e
  unsigned short* g_buf = (unsigned short*)(ws + 71303168);  // 32 MiB bf16 g
  float* P              = (float*)(ws + 104857600);          // 512 KiB
  float* Q              = (float*)(ws + 105381888);          // 512 KiB

  pack_all<<<(NX16 + NW16) / 256, 256, 0, stream>>>(x, Wa, Wx, Xs, Wsz);

  dim3 gg(N_DIM / 128, M_DIM / 128);   // (16, 128), n fastest
  gemm_gates<<<gg, 256, 0, stream>>>(Xs, Wsz, x, ba, bx, lmbd, e_buf, g_buf);

  dim3 sg(D_DIM / 256, NC, B_DIM);     // (4, 32, 4)
  scan_phase1<<<sg, 256, 0, stream>>>(e_buf, g_buf, P, Q);
  scan_phase3<<<sg, 256, 0, stream>>>(e_buf, g_buf, P, Q, y);
}